// Round 1
// baseline (237.144 us; speedup 1.0000x reference)
//
#include <hip/hip_runtime.h>

// ---------------------------------------------------------------------------
// PANet disparity head, fused single kernel for MI355X (gfx950).
//
// Math:  xf,yf = encoder(x), encoder(y)   (B,H,W scalar maps)
//        logits_x[o,w] = yf[w] * sum_d wd[o,d]*xf[w+d] + bd[o]
//        logits_y[o,w] = xf[w] * sum_d wd[o,d]*yf[w-d] + bd[o]
//        disp = sum_o o*softmax_o(logits)
// One block per (b,h) row; encoder + both correlation GEMMs + softmax fused.
// ---------------------------------------------------------------------------

typedef __attribute__((ext_vector_type(8))) __bf16 bf16x8;
typedef __attribute__((ext_vector_type(4))) float  f32x4;

#define MFMA16x16x32(a,b,c) __builtin_amdgcn_mfma_f32_16x16x32_bf16((a),(b),(c),0,0,0)

constexpr int CH = 32, HH = 256, WW = 512, DD = 192;
constexpr int HW  = HH * WW;        // 131072
constexpr int CHW = CH * HW;        // 4194304
constexpr int OUTPLANE = 2 * HH * WW; // 262144 (B*H*W)

// LDS layout (bytes). wd rows are 384 B (192 bf16), XOR-swizzled by (o&7)<<4
// so the b128 A-fragment reads land 4-per-bank (the b128 optimum).
constexpr int WD_OFF  = 0;
constexpr int WD_SZ   = 192 * 384;            // 73728
constexpr int CPS     = 1424;                 // hankel copy stride (712 bf16)
constexpr int XC_OFF  = WD_OFF + WD_SZ;       // 73728: 8 shifted copies of xf
constexpr int YC_OFF  = XC_OFF + 8 * CPS;     // 85120: 8 shifted copies of rev(yf)
constexpr int SCY_OFF = YC_OFF + 8 * CPS;     // 96512: yf f32[512]
constexpr int SCX_OFF = SCY_OFF + 2048;       // 98560: xf f32[512]
constexpr int BD_OFF  = SCX_OFF + 2048;       // 100608: bd f32[192]
constexpr int LDS_BYTES = BD_OFF + 768;       // 101376

__global__ __launch_bounds__(512, 2)
void panet_fused(const float* __restrict__ gx,  const float* __restrict__ gy,
                 const float* __restrict__ gw1, const float* __restrict__ gb1,
                 const float* __restrict__ gw2, const float* __restrict__ gb2,
                 const float* __restrict__ gw3, const float* __restrict__ gb3,
                 const float* __restrict__ gwd, const float* __restrict__ gbd,
                 float* __restrict__ gout)
{
  extern __shared__ __align__(16) char lds[];
  const int tid  = threadIdx.x;
  const int bh   = blockIdx.x;
  const int b    = bh >> 8;
  const int h    = bh & 255;
  const int lane = tid & 63;
  const int m    = lane & 15;   // MFMA row/col within 16
  const int g    = lane >> 4;   // MFMA lane group
  const int wid  = tid >> 6;    // wave id, 8 waves

  // ------------------------------------------------------------- phase 0
  // zero hankel copy regions; stage wd (bf16, swizzled) and bd into LDS.
  {
    int* zp = (int*)(lds + XC_OFF);
    #pragma unroll 4
    for (int i = tid; i < (16 * CPS) / 4; i += 512) zp[i] = 0;

    unsigned short* wds = (unsigned short*)(lds + WD_OFF);
    for (int i = tid; i < 192 * 192; i += 512) {
      const int o = i / 192;
      const int k = i - o * 192;
      const __bf16 v = (__bf16)gwd[i];
      const int byt = o * 384 + ((2 * k) ^ ((o & 7) << 4));
      wds[byt >> 1] = __builtin_bit_cast(unsigned short, v);
    }
    float* bds = (float*)(lds + BD_OFF);
    if (tid < 192) bds[tid] = gbd[tid];
  }
  __syncthreads();

  // ------------------------------------------------------------- phase 1
  // Encoder via MFMA. Slot map for layers 1/2: psi(g,j) = 16*(j>>2)+4g+(j&3)
  // (same bijection used for A and B -> correct regardless of HW k-order).
  // D-fragment (row = 4g+reg) chains directly into layer2's B k-slots.
  {
    bf16x8 A1[4], A2[2][2];
    f32x4  bias1[4], bias2[2], w3v[2];
    #pragma unroll
    for (int Mt = 0; Mt < 4; ++Mt) {
      const float* p = gw1 + (16 * Mt + m) * 32 + 4 * g;
      const f32x4 u0 = *(const f32x4*)p;
      const f32x4 u1 = *(const f32x4*)(p + 16);
      #pragma unroll
      for (int j = 0; j < 4; ++j) { A1[Mt][j] = (__bf16)u0[j]; A1[Mt][j + 4] = (__bf16)u1[j]; }
      bias1[Mt] = *(const f32x4*)(gb1 + 16 * Mt + 4 * g);
    }
    #pragma unroll
    for (int Mt = 0; Mt < 2; ++Mt) {
      #pragma unroll
      for (int s = 0; s < 2; ++s) {
        const float* p = gw2 + (16 * Mt + m) * 64 + 32 * s + 4 * g;
        const f32x4 u0 = *(const f32x4*)p;
        const f32x4 u1 = *(const f32x4*)(p + 16);
        #pragma unroll
        for (int j = 0; j < 4; ++j) { A2[Mt][s][j] = (__bf16)u0[j]; A2[Mt][s][j + 4] = (__bf16)u1[j]; }
      }
      bias2[Mt] = *(const f32x4*)(gb2 + 16 * Mt + 4 * g);
      w3v[Mt]   = *(const f32x4*)(gw3 + 16 * Mt + 4 * g);
    }
    const float b3s = gb3[0];
    const f32x4 zf4 = {0.f, 0.f, 0.f, 0.f};

    for (int u = wid; u < 64; u += 8) {          // 2 images x 32 col-tiles
      const int t  = u >> 5;
      const int w0 = (u & 31) << 4;
      const float* src = (t ? gy : gx) + b * CHW + h * WW + w0 + m;

      bf16x8 B1;                                  // relu(x) channel fragment
      #pragma unroll
      for (int j = 0; j < 8; ++j) {
        const int c = 16 * (j >> 2) + 4 * g + (j & 3);
        B1[j] = (__bf16)fmaxf(src[c * HW], 0.f);
      }
      f32x4 acc1[4];
      #pragma unroll
      for (int Mt = 0; Mt < 4; ++Mt) acc1[Mt] = MFMA16x16x32(A1[Mt], B1, zf4);

      bf16x8 B2[2];                               // layer1 -> layer2 in-register
      #pragma unroll
      for (int s = 0; s < 2; ++s) {
        #pragma unroll
        for (int j = 0; j < 4; ++j) {
          B2[s][j]     = (__bf16)fmaxf(acc1[2 * s][j]     + bias1[2 * s][j],     0.f);
          B2[s][j + 4] = (__bf16)fmaxf(acc1[2 * s + 1][j] + bias1[2 * s + 1][j], 0.f);
        }
      }
      f32x4 acc2[2];
      #pragma unroll
      for (int Mt = 0; Mt < 2; ++Mt)
        acc2[Mt] = MFMA16x16x32(A2[Mt][1], B2[1], MFMA16x16x32(A2[Mt][0], B2[0], zf4));

      float s3 = 0.f;                             // layer3 (1x32) in VALU
      #pragma unroll
      for (int Mt = 0; Mt < 2; ++Mt)
        #pragma unroll
        for (int r = 0; r < 4; ++r)
          s3 += w3v[Mt][r] * fmaxf(acc2[Mt][r] + bias2[Mt][r], 0.f);
      s3 += __shfl_xor(s3, 16);
      s3 += __shfl_xor(s3, 32);
      const float val = fmaxf(s3 + b3s, 0.f);

      if (lane < 16) {
        const int px = w0 + m;
        const unsigned short bits = __builtin_bit_cast(unsigned short, (__bf16)val);
        if (t == 0) {
          ((float*)(lds + SCX_OFF))[px] = val;
          #pragma unroll
          for (int c = 0; c < 8; ++c) {           // copy_c[e] = xf[e+c]
            const int e = px - c;
            if (e >= 0) ((unsigned short*)(lds + XC_OFF + c * CPS))[e] = bits;
          }
        } else {
          ((float*)(lds + SCY_OFF))[px] = val;
          #pragma unroll
          for (int c = 0; c < 8; ++c) {           // rev copy: ry[e] = yf[511-e]
            const int e = 511 - px - c;
            if (e >= 0) ((unsigned short*)(lds + YC_OFF + c * CPS))[e] = bits;
          }
        }
      }
    }
  }
  __syncthreads();

  // ------------------------------------------------------------- phase 2
  // Correlation GEMM (A = wd 192x192, B = hankel 192x512) + fused softmax.
  // Slot map here: psi(g,j) = 8g+j (contiguous 8 -> one b128 per fragment).
  // Waves 0-3: x-direction, waves 4-7: y-direction; 128 cols per wave.
  {
    const int dir      = wid >> 2;
    const int colbase  = (wid & 3) << 7;
    const char* Bb     = lds + (dir ? YC_OFF : XC_OFF);
    const float* scrow = (const float*)(lds + (dir ? SCX_OFF : SCY_OFF));
    float* outp = gout + dir * OUTPLANE + (((b << 8) + h) << 9);
    const int Xm   = (m & 7) << 4;
    const int arow = m * 384;

    for (int chunk = 0; chunk < 4; ++chunk) {
      const int n0 = colbase + (chunk << 5);
      int laneB[2];
      #pragma unroll
      for (int nt = 0; nt < 2; ++nt) {
        const int wc = n0 + 16 * nt + m;
        const int I0 = dir ? (511 - wc) : wc;     // hankel base element
        const int c  = I0 & 7;                    // which shifted copy
        laneB[nt] = c * CPS + 2 * (I0 - c) + 16 * g;
      }
      f32x4 acc[12][2];
      #pragma unroll
      for (int Mt = 0; Mt < 12; ++Mt) { acc[Mt][0] = {0,0,0,0}; acc[Mt][1] = {0,0,0,0}; }

      #pragma unroll
      for (int ks = 0; ks < 6; ++ks) {            // K = 6*32 = 192
        const int inner = ((ks << 6) + (g << 4)) ^ Xm;
        const bf16x8 bf0 = *(const bf16x8*)(Bb + laneB[0] + (ks << 6));
        const bf16x8 bf1 = *(const bf16x8*)(Bb + laneB[1] + (ks << 6));
        #pragma unroll
        for (int Mt = 0; Mt < 12; ++Mt) {
          const bf16x8 af = *(const bf16x8*)(lds + WD_OFF + Mt * 6144 + arow + inner);
          acc[Mt][0] = MFMA16x16x32(af, bf0, acc[Mt][0]);
          acc[Mt][1] = MFMA16x16x32(af, bf1, acc[Mt][1]);
        }
      }

      // fused scale + bias + softmax + expectation (all 64 lanes active)
      #pragma unroll
      for (int nt = 0; nt < 2; ++nt) {
        const int wc = n0 + 16 * nt + m;
        const float sc = scrow[wc];
        float mx = -3.4e38f;
        #pragma unroll
        for (int Mt = 0; Mt < 12; ++Mt) {
          const f32x4 bdv = *(const f32x4*)(lds + BD_OFF + 64 * Mt + 16 * g);
          #pragma unroll
          for (int r = 0; r < 4; ++r) {
            const float L = fmaf(sc, acc[Mt][nt][r], bdv[r]);
            acc[Mt][nt][r] = L;
            mx = fmaxf(mx, L);
          }
        }
        mx = fmaxf(mx, __shfl_xor(mx, 16));
        mx = fmaxf(mx, __shfl_xor(mx, 32));
        float sum = 0.f, wsum = 0.f;
        #pragma unroll
        for (int Mt = 0; Mt < 12; ++Mt) {
          #pragma unroll
          for (int r = 0; r < 4; ++r) {
            const float p = __expf(acc[Mt][nt][r] - mx);
            sum += p;
            wsum = fmaf((float)(16 * Mt + r), p, wsum);  // o = 16Mt + 4g + r
          }
        }
        wsum = fmaf(4.f * (float)g, sum, wsum);
        sum  += __shfl_xor(sum, 16);  sum  += __shfl_xor(sum, 32);
        wsum += __shfl_xor(wsum, 16); wsum += __shfl_xor(wsum, 32);
        if (lane < 16) outp[wc] = wsum / sum;
      }
    }
  }
}

extern "C" void kernel_launch(void* const* d_in, const int* in_sizes, int n_in,
                              void* d_out, int out_size, void* d_ws, size_t ws_size,
                              hipStream_t stream) {
  const float* x  = (const float*)d_in[0];
  const float* y  = (const float*)d_in[1];
  const float* w1 = (const float*)d_in[2];
  const float* b1 = (const float*)d_in[3];
  const float* w2 = (const float*)d_in[4];
  const float* b2 = (const float*)d_in[5];
  const float* w3 = (const float*)d_in[6];
  const float* b3 = (const float*)d_in[7];
  const float* wd = (const float*)d_in[8];
  const float* bd = (const float*)d_in[9];

  // >64KB dynamic LDS: set the opt-in attribute (harmless if not required).
  (void)hipFuncSetAttribute((const void*)panet_fused,
                            hipFuncAttributeMaxDynamicSharedMemorySize, LDS_BYTES);
  panet_fused<<<512, 512, LDS_BYTES, stream>>>(x, y, w1, b1, w2, b2, w3, b3, wd, bd,
                                               (float*)d_out);
}

// Round 2
// 233.230 us; speedup vs baseline: 1.0168x; 1.0168x over previous
//
#include <hip/hip_runtime.h>

// ---------------------------------------------------------------------------
// PANet disparity head, fused single kernel for MI355X (gfx950).
//
// Math:  xf,yf = encoder(x), encoder(y)   (B,H,W scalar maps)
//        logits_x[o,w] = yf[w] * sum_d wd[o,d]*xf[w+d] + bd[o]
//        logits_y[o,w] = xf[w] * sum_d wd[o,d]*yf[w-d] + bd[o]
//        disp = sum_o o*softmax_o(logits)
// One block per (b,h) row; encoder + both correlation GEMMs + softmax fused.
//
// R1 lesson: __launch_bounds__(512,2) capped VGPRs at 128 -> the 96-reg
// phase-2 accumulator spilled to scratch (258 MB writes vs 2 MB output).
// LDS (101 KB) limits us to 1 block/CU regardless, so declare (512,1).
// ---------------------------------------------------------------------------

typedef __attribute__((ext_vector_type(8))) __bf16 bf16x8;
typedef __attribute__((ext_vector_type(4))) float  f32x4;

#define MFMA16x16x32(a,b,c) __builtin_amdgcn_mfma_f32_16x16x32_bf16((a),(b),(c),0,0,0)

constexpr int CH = 32, HH = 256, WW = 512, DD = 192;
constexpr int HW  = HH * WW;        // 131072
constexpr int CHW = CH * HW;        // 4194304
constexpr int OUTPLANE = 2 * HH * WW; // 262144 (B*H*W)

// LDS layout (bytes). wd rows are 384 B (192 bf16), XOR-swizzled by (o&7)<<4
// so the b128 A-fragment reads land 4-per-bank (the b128 optimum).
constexpr int WD_OFF  = 0;
constexpr int WD_SZ   = 192 * 384;            // 73728
constexpr int CPS     = 1424;                 // hankel copy stride (712 bf16)
constexpr int XC_OFF  = WD_OFF + WD_SZ;       // 73728: 8 shifted copies of xf
constexpr int YC_OFF  = XC_OFF + 8 * CPS;     // 85120: 8 shifted copies of rev(yf)
constexpr int SCY_OFF = YC_OFF + 8 * CPS;     // 96512: yf f32[512]
constexpr int SCX_OFF = SCY_OFF + 2048;       // 98560: xf f32[512]
constexpr int BD_OFF  = SCX_OFF + 2048;       // 100608: bd f32[192]
constexpr int LDS_BYTES = BD_OFF + 768;       // 101376

__global__ __launch_bounds__(512, 1)
void panet_fused(const float* __restrict__ gx,  const float* __restrict__ gy,
                 const float* __restrict__ gw1, const float* __restrict__ gb1,
                 const float* __restrict__ gw2, const float* __restrict__ gb2,
                 const float* __restrict__ gw3, const float* __restrict__ gb3,
                 const float* __restrict__ gwd, const float* __restrict__ gbd,
                 float* __restrict__ gout)
{
  extern __shared__ __align__(16) char lds[];
  const int tid  = threadIdx.x;
  const int bh   = blockIdx.x;
  const int b    = bh >> 8;
  const int h    = bh & 255;
  const int lane = tid & 63;
  const int m    = lane & 15;   // MFMA row/col within 16
  const int g    = lane >> 4;   // MFMA lane group
  const int wid  = tid >> 6;    // wave id, 8 waves

  // ------------------------------------------------------------- phase 0
  // zero hankel copy regions; stage wd (bf16, swizzled) and bd into LDS.
  {
    int* zp = (int*)(lds + XC_OFF);
    #pragma unroll 4
    for (int i = tid; i < (16 * CPS) / 4; i += 512) zp[i] = 0;

    unsigned short* wds = (unsigned short*)(lds + WD_OFF);
    for (int i = tid; i < 192 * 192; i += 512) {
      const int o = i / 192;
      const int k = i - o * 192;
      const __bf16 v = (__bf16)gwd[i];
      const int byt = o * 384 + ((2 * k) ^ ((o & 7) << 4));
      wds[byt >> 1] = __builtin_bit_cast(unsigned short, v);
    }
    float* bds = (float*)(lds + BD_OFF);
    if (tid < 192) bds[tid] = gbd[tid];
  }
  __syncthreads();

  // ------------------------------------------------------------- phase 1
  // Encoder via MFMA. Slot map for layers 1/2: psi(g,j) = 16*(j>>2)+4g+(j&3)
  // (same bijection used for A and B -> correct regardless of HW k-order).
  // D-fragment (row = 4g+reg) chains directly into layer2's B k-slots.
  {
    bf16x8 A1[4], A2[2][2];
    f32x4  bias1[4], bias2[2], w3v[2];
    #pragma unroll
    for (int Mt = 0; Mt < 4; ++Mt) {
      const float* p = gw1 + (16 * Mt + m) * 32 + 4 * g;
      const f32x4 u0 = *(const f32x4*)p;
      const f32x4 u1 = *(const f32x4*)(p + 16);
      #pragma unroll
      for (int j = 0; j < 4; ++j) { A1[Mt][j] = (__bf16)u0[j]; A1[Mt][j + 4] = (__bf16)u1[j]; }
      bias1[Mt] = *(const f32x4*)(gb1 + 16 * Mt + 4 * g);
    }
    #pragma unroll
    for (int Mt = 0; Mt < 2; ++Mt) {
      #pragma unroll
      for (int s = 0; s < 2; ++s) {
        const float* p = gw2 + (16 * Mt + m) * 64 + 32 * s + 4 * g;
        const f32x4 u0 = *(const f32x4*)p;
        const f32x4 u1 = *(const f32x4*)(p + 16);
        #pragma unroll
        for (int j = 0; j < 4; ++j) { A2[Mt][s][j] = (__bf16)u0[j]; A2[Mt][s][j + 4] = (__bf16)u1[j]; }
      }
      bias2[Mt] = *(const f32x4*)(gb2 + 16 * Mt + 4 * g);
      w3v[Mt]   = *(const f32x4*)(gw3 + 16 * Mt + 4 * g);
    }
    const float b3s = gb3[0];
    const f32x4 zf4 = {0.f, 0.f, 0.f, 0.f};

    for (int u = wid; u < 64; u += 8) {          // 2 images x 32 col-tiles
      const int t  = u >> 5;
      const int w0 = (u & 31) << 4;
      const float* src = (t ? gy : gx) + b * CHW + h * WW + w0 + m;

      bf16x8 B1;                                  // relu(x) channel fragment
      #pragma unroll
      for (int j = 0; j < 8; ++j) {
        const int c = 16 * (j >> 2) + 4 * g + (j & 3);
        B1[j] = (__bf16)fmaxf(src[c * HW], 0.f);
      }
      f32x4 acc1[4];
      #pragma unroll
      for (int Mt = 0; Mt < 4; ++Mt) acc1[Mt] = MFMA16x16x32(A1[Mt], B1, zf4);

      bf16x8 B2[2];                               // layer1 -> layer2 in-register
      #pragma unroll
      for (int s = 0; s < 2; ++s) {
        #pragma unroll
        for (int j = 0; j < 4; ++j) {
          B2[s][j]     = (__bf16)fmaxf(acc1[2 * s][j]     + bias1[2 * s][j],     0.f);
          B2[s][j + 4] = (__bf16)fmaxf(acc1[2 * s + 1][j] + bias1[2 * s + 1][j], 0.f);
        }
      }
      f32x4 acc2[2];
      #pragma unroll
      for (int Mt = 0; Mt < 2; ++Mt)
        acc2[Mt] = MFMA16x16x32(A2[Mt][1], B2[1], MFMA16x16x32(A2[Mt][0], B2[0], zf4));

      float s3 = 0.f;                             // layer3 (1x32) in VALU
      #pragma unroll
      for (int Mt = 0; Mt < 2; ++Mt)
        #pragma unroll
        for (int r = 0; r < 4; ++r)
          s3 += w3v[Mt][r] * fmaxf(acc2[Mt][r] + bias2[Mt][r], 0.f);
      s3 += __shfl_xor(s3, 16);
      s3 += __shfl_xor(s3, 32);
      const float val = fmaxf(s3 + b3s, 0.f);

      if (lane < 16) {
        const int px = w0 + m;
        const unsigned short bits = __builtin_bit_cast(unsigned short, (__bf16)val);
        if (t == 0) {
          ((float*)(lds + SCX_OFF))[px] = val;
          #pragma unroll
          for (int c = 0; c < 8; ++c) {           // copy_c[e] = xf[e+c]
            const int e = px - c;
            if (e >= 0) ((unsigned short*)(lds + XC_OFF + c * CPS))[e] = bits;
          }
        } else {
          ((float*)(lds + SCY_OFF))[px] = val;
          #pragma unroll
          for (int c = 0; c < 8; ++c) {           // rev copy: ry[e] = yf[511-e]
            const int e = 511 - px - c;
            if (e >= 0) ((unsigned short*)(lds + YC_OFF + c * CPS))[e] = bits;
          }
        }
      }
    }
  }
  __syncthreads();

  // ------------------------------------------------------------- phase 2
  // Correlation GEMM (A = wd 192x192, B = hankel 192x512) + fused softmax.
  // Slot map here: psi(g,j) = 8g+j (contiguous 8 -> one b128 per fragment).
  // Waves 0-3: x-direction, waves 4-7: y-direction; 128 cols per wave.
  {
    const int dir      = wid >> 2;
    const int colbase  = (wid & 3) << 7;
    const char* Bb     = lds + (dir ? YC_OFF : XC_OFF);
    const float* scrow = (const float*)(lds + (dir ? SCX_OFF : SCY_OFF));
    float* outp = gout + dir * OUTPLANE + (((b << 8) + h) << 9);
    const int Xm   = (m & 7) << 4;
    const int arow = m * 384;

    for (int chunk = 0; chunk < 4; ++chunk) {
      const int n0 = colbase + (chunk << 5);
      int laneB[2];
      #pragma unroll
      for (int nt = 0; nt < 2; ++nt) {
        const int wc = n0 + 16 * nt + m;
        const int I0 = dir ? (511 - wc) : wc;     // hankel base element
        const int c  = I0 & 7;                    // which shifted copy
        laneB[nt] = c * CPS + 2 * (I0 - c) + 16 * g;
      }
      f32x4 acc[12][2];
      #pragma unroll
      for (int Mt = 0; Mt < 12; ++Mt) { acc[Mt][0] = {0,0,0,0}; acc[Mt][1] = {0,0,0,0}; }

      #pragma unroll
      for (int ks = 0; ks < 6; ++ks) {            // K = 6*32 = 192
        const int inner = ((ks << 6) + (g << 4)) ^ Xm;
        const bf16x8 bf0 = *(const bf16x8*)(Bb + laneB[0] + (ks << 6));
        const bf16x8 bf1 = *(const bf16x8*)(Bb + laneB[1] + (ks << 6));
        #pragma unroll
        for (int Mt = 0; Mt < 12; ++Mt) {
          const bf16x8 af = *(const bf16x8*)(lds + WD_OFF + Mt * 6144 + arow + inner);
          acc[Mt][0] = MFMA16x16x32(af, bf0, acc[Mt][0]);
          acc[Mt][1] = MFMA16x16x32(af, bf1, acc[Mt][1]);
        }
      }

      // fused scale + bias + softmax + expectation (all 64 lanes active)
      #pragma unroll
      for (int nt = 0; nt < 2; ++nt) {
        const int wc = n0 + 16 * nt + m;
        const float sc = scrow[wc];
        float mx = -3.4e38f;
        #pragma unroll
        for (int Mt = 0; Mt < 12; ++Mt) {
          const f32x4 bdv = *(const f32x4*)(lds + BD_OFF + 64 * Mt + 16 * g);
          #pragma unroll
          for (int r = 0; r < 4; ++r) {
            const float L = fmaf(sc, acc[Mt][nt][r], bdv[r]);
            acc[Mt][nt][r] = L;
            mx = fmaxf(mx, L);
          }
        }
        mx = fmaxf(mx, __shfl_xor(mx, 16));
        mx = fmaxf(mx, __shfl_xor(mx, 32));
        float sum = 0.f, wsum = 0.f;
        #pragma unroll
        for (int Mt = 0; Mt < 12; ++Mt) {
          #pragma unroll
          for (int r = 0; r < 4; ++r) {
            const float p = __expf(acc[Mt][nt][r] - mx);
            sum += p;
            wsum = fmaf((float)(16 * Mt + r), p, wsum);  // o = 16Mt + 4g + r
          }
        }
        wsum = fmaf(4.f * (float)g, sum, wsum);
        sum  += __shfl_xor(sum, 16);  sum  += __shfl_xor(sum, 32);
        wsum += __shfl_xor(wsum, 16); wsum += __shfl_xor(wsum, 32);
        if (lane < 16) outp[wc] = wsum / sum;
      }
    }
  }
}

extern "C" void kernel_launch(void* const* d_in, const int* in_sizes, int n_in,
                              void* d_out, int out_size, void* d_ws, size_t ws_size,
                              hipStream_t stream) {
  const float* x  = (const float*)d_in[0];
  const float* y  = (const float*)d_in[1];
  const float* w1 = (const float*)d_in[2];
  const float* b1 = (const float*)d_in[3];
  const float* w2 = (const float*)d_in[4];
  const float* b2 = (const float*)d_in[5];
  const float* w3 = (const float*)d_in[6];
  const float* b3 = (const float*)d_in[7];
  const float* wd = (const float*)d_in[8];
  const float* bd = (const float*)d_in[9];

  // >64KB dynamic LDS: set the opt-in attribute (harmless if not required).
  (void)hipFuncSetAttribute((const void*)panet_fused,
                            hipFuncAttributeMaxDynamicSharedMemorySize, LDS_BYTES);
  panet_fused<<<512, 512, LDS_BYTES, stream>>>(x, y, w1, b1, w2, b2, w3, b3, wd, bd,
                                               (float*)d_out);
}

// Round 3
// 91.030 us; speedup vs baseline: 2.6051x; 2.5621x over previous
//
#include <hip/hip_runtime.h>

// ---------------------------------------------------------------------------
// PANet disparity head, fused single kernel for MI355X (gfx950).
//
// Math:  xf,yf = encoder(x), encoder(y)   (B,H,W scalar maps)
//        logits_x[o,w] = yf[w] * sum_d wd[o,d]*xf[w+d] + bd[o]
//        logits_y[o,w] = xf[w] * sum_d wd[o,d]*yf[w-d] + bd[o]
//        disp = sum_o o*softmax_o(logits)
// One block per (b,h) row; encoder + both correlation GEMMs + softmax fused.
//
// R1/R2 lesson: 258 MB of scratch writes (output is 2 MB) — phase-2 register
// state spilled at the compiler's 128-VGPR choice; launch_bounds minimum did
// NOT move it (dynamic LDS hides the occupancy limit from the allocator).
// R3: (a) amdgpu_waves_per_eu(2,2) -> 256-VGPR budget; (b) restructure
// phase 2: hoist B-fragments, iterate Mt in pairs with ONLINE softmax so the
// live set fits ~120 VGPRs even under a 128 cap.
// ---------------------------------------------------------------------------

typedef __attribute__((ext_vector_type(8))) __bf16 bf16x8;
typedef __attribute__((ext_vector_type(4))) float  f32x4;

#define MFMA16x16x32(a,b,c) __builtin_amdgcn_mfma_f32_16x16x32_bf16((a),(b),(c),0,0,0)

constexpr int CH = 32, HH = 256, WW = 512, DD = 192;
constexpr int HW  = HH * WW;        // 131072
constexpr int CHW = CH * HW;        // 4194304
constexpr int OUTPLANE = 2 * HH * WW; // 262144 (B*H*W)

// LDS layout (bytes). wd rows are 384 B (192 bf16), XOR-swizzled by (o&7)<<4.
constexpr int WD_OFF  = 0;
constexpr int WD_SZ   = 192 * 384;            // 73728
constexpr int CPS     = 1424;                 // hankel copy stride (712 bf16)
constexpr int XC_OFF  = WD_OFF + WD_SZ;       // 73728: 8 shifted copies of xf
constexpr int YC_OFF  = XC_OFF + 8 * CPS;     // 85120: 8 shifted copies of rev(yf)
constexpr int SCY_OFF = YC_OFF + 8 * CPS;     // 96512: yf f32[512]
constexpr int SCX_OFF = SCY_OFF + 2048;       // 98560: xf f32[512]
constexpr int BD_OFF  = SCX_OFF + 2048;       // 100608: bd f32[192]
constexpr int LDS_BYTES = BD_OFF + 768;       // 101376

__global__ __launch_bounds__(512)
__attribute__((amdgpu_waves_per_eu(2, 2)))
void panet_fused(const float* __restrict__ gx,  const float* __restrict__ gy,
                 const float* __restrict__ gw1, const float* __restrict__ gb1,
                 const float* __restrict__ gw2, const float* __restrict__ gb2,
                 const float* __restrict__ gw3, const float* __restrict__ gb3,
                 const float* __restrict__ gwd, const float* __restrict__ gbd,
                 float* __restrict__ gout)
{
  extern __shared__ __align__(16) char lds[];
  const int tid  = threadIdx.x;
  const int bh   = blockIdx.x;
  const int b    = bh >> 8;
  const int h    = bh & 255;
  const int lane = tid & 63;
  const int m    = lane & 15;   // MFMA row/col within 16
  const int g    = lane >> 4;   // MFMA lane group
  const int wid  = tid >> 6;    // wave id, 8 waves

  // ------------------------------------------------------------- phase 0
  {
    int* zp = (int*)(lds + XC_OFF);
    #pragma unroll 4
    for (int i = tid; i < (16 * CPS) / 4; i += 512) zp[i] = 0;

    unsigned short* wds = (unsigned short*)(lds + WD_OFF);
    for (int i = tid; i < 192 * 192; i += 512) {
      const int o = i / 192;
      const int k = i - o * 192;
      const __bf16 v = (__bf16)gwd[i];
      const int byt = o * 384 + ((2 * k) ^ ((o & 7) << 4));
      wds[byt >> 1] = __builtin_bit_cast(unsigned short, v);
    }
    float* bds = (float*)(lds + BD_OFF);
    if (tid < 192) bds[tid] = gbd[tid];
  }
  __syncthreads();

  // ------------------------------------------------------------- phase 1
  // Encoder via MFMA. Slot map for layers 1/2: psi(g,j) = 16*(j>>2)+4g+(j&3).
  {
    bf16x8 A1[4], A2[2][2];
    f32x4  bias1[4], bias2[2], w3v[2];
    #pragma unroll
    for (int Mt = 0; Mt < 4; ++Mt) {
      const float* p = gw1 + (16 * Mt + m) * 32 + 4 * g;
      const f32x4 u0 = *(const f32x4*)p;
      const f32x4 u1 = *(const f32x4*)(p + 16);
      #pragma unroll
      for (int j = 0; j < 4; ++j) { A1[Mt][j] = (__bf16)u0[j]; A1[Mt][j + 4] = (__bf16)u1[j]; }
      bias1[Mt] = *(const f32x4*)(gb1 + 16 * Mt + 4 * g);
    }
    #pragma unroll
    for (int Mt = 0; Mt < 2; ++Mt) {
      #pragma unroll
      for (int s = 0; s < 2; ++s) {
        const float* p = gw2 + (16 * Mt + m) * 64 + 32 * s + 4 * g;
        const f32x4 u0 = *(const f32x4*)p;
        const f32x4 u1 = *(const f32x4*)(p + 16);
        #pragma unroll
        for (int j = 0; j < 4; ++j) { A2[Mt][s][j] = (__bf16)u0[j]; A2[Mt][s][j + 4] = (__bf16)u1[j]; }
      }
      bias2[Mt] = *(const f32x4*)(gb2 + 16 * Mt + 4 * g);
      w3v[Mt]   = *(const f32x4*)(gw3 + 16 * Mt + 4 * g);
    }
    const float b3s = gb3[0];
    const f32x4 zf4 = {0.f, 0.f, 0.f, 0.f};

    for (int u = wid; u < 64; u += 8) {          // 2 images x 32 col-tiles
      const int t  = u >> 5;
      const int w0 = (u & 31) << 4;
      const float* src = (t ? gy : gx) + b * CHW + h * WW + w0 + m;

      bf16x8 B1;
      #pragma unroll
      for (int j = 0; j < 8; ++j) {
        const int c = 16 * (j >> 2) + 4 * g + (j & 3);
        B1[j] = (__bf16)fmaxf(src[c * HW], 0.f);
      }
      f32x4 acc1[4];
      #pragma unroll
      for (int Mt = 0; Mt < 4; ++Mt) acc1[Mt] = MFMA16x16x32(A1[Mt], B1, zf4);

      bf16x8 B2[2];
      #pragma unroll
      for (int s = 0; s < 2; ++s) {
        #pragma unroll
        for (int j = 0; j < 4; ++j) {
          B2[s][j]     = (__bf16)fmaxf(acc1[2 * s][j]     + bias1[2 * s][j],     0.f);
          B2[s][j + 4] = (__bf16)fmaxf(acc1[2 * s + 1][j] + bias1[2 * s + 1][j], 0.f);
        }
      }
      f32x4 acc2[2];
      #pragma unroll
      for (int Mt = 0; Mt < 2; ++Mt)
        acc2[Mt] = MFMA16x16x32(A2[Mt][1], B2[1], MFMA16x16x32(A2[Mt][0], B2[0], zf4));

      float s3 = 0.f;
      #pragma unroll
      for (int Mt = 0; Mt < 2; ++Mt)
        #pragma unroll
        for (int r = 0; r < 4; ++r)
          s3 += w3v[Mt][r] * fmaxf(acc2[Mt][r] + bias2[Mt][r], 0.f);
      s3 += __shfl_xor(s3, 16);
      s3 += __shfl_xor(s3, 32);
      const float val = fmaxf(s3 + b3s, 0.f);

      if (lane < 16) {
        const int px = w0 + m;
        const unsigned short bits = __builtin_bit_cast(unsigned short, (__bf16)val);
        if (t == 0) {
          ((float*)(lds + SCX_OFF))[px] = val;
          #pragma unroll
          for (int c = 0; c < 8; ++c) {           // copy_c[e] = xf[e+c]
            const int e = px - c;
            if (e >= 0) ((unsigned short*)(lds + XC_OFF + c * CPS))[e] = bits;
          }
        } else {
          ((float*)(lds + SCY_OFF))[px] = val;
          #pragma unroll
          for (int c = 0; c < 8; ++c) {           // rev copy: ry[e] = yf[511-e]
            const int e = 511 - px - c;
            if (e >= 0) ((unsigned short*)(lds + YC_OFF + c * CPS))[e] = bits;
          }
        }
      }
    }
  }
  __syncthreads();

  // ------------------------------------------------------------- phase 2
  // Correlation GEMM + ONLINE softmax. B-fragments hoisted (48 VGPRs), then
  // 192 output rows processed in 6 Mt-pairs; per pair only 16 acc regs live.
  // Waves 0-3: x-direction, waves 4-7: y-direction; 128 cols per wave.
  {
    const int dir      = wid >> 2;
    const int colbase  = (wid & 3) << 7;
    const char* Bb     = lds + (dir ? YC_OFF : XC_OFF);
    const float* scrow = (const float*)(lds + (dir ? SCX_OFF : SCY_OFF));
    float* outp = gout + dir * OUTPLANE + (((b << 8) + h) << 9);
    const int Xm   = (m & 7) << 4;
    const int arow = m * 384;
    const float g4 = 4.0f * (float)g;

    for (int chunk = 0; chunk < 4; ++chunk) {
      const int n0 = colbase + (chunk << 5);
      int   laneB[2];
      float sc[2];
      #pragma unroll
      for (int nt = 0; nt < 2; ++nt) {
        const int wc = n0 + 16 * nt + m;
        const int I0 = dir ? (511 - wc) : wc;     // hankel base element
        const int c  = I0 & 7;                    // which shifted copy
        laneB[nt] = c * CPS + 2 * (I0 - c) + 16 * g;
        sc[nt] = scrow[wc];
      }
      bf16x8 bfr[6][2];
      #pragma unroll
      for (int ks = 0; ks < 6; ++ks) {            // K = 6*32 = 192
        bfr[ks][0] = *(const bf16x8*)(Bb + laneB[0] + (ks << 6));
        bfr[ks][1] = *(const bf16x8*)(Bb + laneB[1] + (ks << 6));
      }

      float mx0 = -3.4e38f, mx1 = -3.4e38f;
      float s0 = 0.f, s1 = 0.f, ws0 = 0.f, ws1 = 0.f;

      #pragma unroll 2
      for (int mp = 0; mp < 6; ++mp) {            // Mt pair = rows 32mp..32mp+31
        f32x4 a00 = {0,0,0,0}, a01 = {0,0,0,0}, a10 = {0,0,0,0}, a11 = {0,0,0,0};
        #pragma unroll
        for (int ks = 0; ks < 6; ++ks) {
          const int inner = ((ks << 6) + (g << 4)) ^ Xm;
          const char* ap = lds + WD_OFF + (mp * 2) * 6144 + arow + inner;
          const bf16x8 af0 = *(const bf16x8*)(ap);
          const bf16x8 af1 = *(const bf16x8*)(ap + 6144);
          a00 = MFMA16x16x32(af0, bfr[ks][0], a00);
          a01 = MFMA16x16x32(af0, bfr[ks][1], a01);
          a10 = MFMA16x16x32(af1, bfr[ks][0], a10);
          a11 = MFMA16x16x32(af1, bfr[ks][1], a11);
        }
        const f32x4 bd0 = *(const f32x4*)(lds + BD_OFF + (mp * 2) * 64 + 16 * g);
        const f32x4 bd1 = *(const f32x4*)(lds + BD_OFF + (mp * 2 + 1) * 64 + 16 * g);
        const float ob = (float)(32 * mp);        // o = 32mp + 16tt + 4g + r (4g added at end)

        {                                          // nt = 0
          f32x4 L0, L1;
          #pragma unroll
          for (int r = 0; r < 4; ++r) {
            L0[r] = fmaf(sc[0], a00[r], bd0[r]);
            L1[r] = fmaf(sc[0], a10[r], bd1[r]);
          }
          const float pm = fmaxf(fmaxf(fmaxf(L0[0], L0[1]), fmaxf(L0[2], L0[3])),
                                 fmaxf(fmaxf(L1[0], L1[1]), fmaxf(L1[2], L1[3])));
          const float nm = fmaxf(mx0, pm);
          const float f  = __expf(mx0 - nm);
          float ls = 0.f, lw = 0.f;
          #pragma unroll
          for (int r = 0; r < 4; ++r) {
            const float p0 = __expf(L0[r] - nm);
            const float p1 = __expf(L1[r] - nm);
            ls += p0 + p1;
            lw += (ob + (float)r) * p0 + (ob + 16.f + (float)r) * p1;
          }
          s0  = fmaf(s0,  f, ls);
          ws0 = fmaf(ws0, f, lw);
          mx0 = nm;
        }
        {                                          // nt = 1
          f32x4 L0, L1;
          #pragma unroll
          for (int r = 0; r < 4; ++r) {
            L0[r] = fmaf(sc[1], a01[r], bd0[r]);
            L1[r] = fmaf(sc[1], a11[r], bd1[r]);
          }
          const float pm = fmaxf(fmaxf(fmaxf(L0[0], L0[1]), fmaxf(L0[2], L0[3])),
                                 fmaxf(fmaxf(L1[0], L1[1]), fmaxf(L1[2], L1[3])));
          const float nm = fmaxf(mx1, pm);
          const float f  = __expf(mx1 - nm);
          float ls = 0.f, lw = 0.f;
          #pragma unroll
          for (int r = 0; r < 4; ++r) {
            const float p0 = __expf(L0[r] - nm);
            const float p1 = __expf(L1[r] - nm);
            ls += p0 + p1;
            lw += (ob + (float)r) * p0 + (ob + 16.f + (float)r) * p1;
          }
          s1  = fmaf(s1,  f, ls);
          ws1 = fmaf(ws1, f, lw);
          mx1 = nm;
        }
      }

      // cross-lane combine: rescale each lane's partial to the group max first
      #pragma unroll
      for (int nt = 0; nt < 2; ++nt) {
        const float mx = nt ? mx1 : mx0;
        const float s  = nt ? s1  : s0;
        const float ws = nt ? ws1 : ws0;
        float M = fmaxf(mx, __shfl_xor(mx, 16));
        M = fmaxf(M, __shfl_xor(M, 32));
        const float f = __expf(mx - M);
        float sr = s * f;
        float wr = (ws + g4 * s) * f;
        sr += __shfl_xor(sr, 16); sr += __shfl_xor(sr, 32);
        wr += __shfl_xor(wr, 16); wr += __shfl_xor(wr, 32);
        if (lane < 16) outp[n0 + 16 * nt + m] = wr / sr;
      }
    }
  }
}

extern "C" void kernel_launch(void* const* d_in, const int* in_sizes, int n_in,
                              void* d_out, int out_size, void* d_ws, size_t ws_size,
                              hipStream_t stream) {
  const float* x  = (const float*)d_in[0];
  const float* y  = (const float*)d_in[1];
  const float* w1 = (const float*)d_in[2];
  const float* b1 = (const float*)d_in[3];
  const float* w2 = (const float*)d_in[4];
  const float* b2 = (const float*)d_in[5];
  const float* w3 = (const float*)d_in[6];
  const float* b3 = (const float*)d_in[7];
  const float* wd = (const float*)d_in[8];
  const float* bd = (const float*)d_in[9];

  // >64KB dynamic LDS: set the opt-in attribute (harmless if not required).
  (void)hipFuncSetAttribute((const void*)panet_fused,
                            hipFuncAttributeMaxDynamicSharedMemorySize, LDS_BYTES);
  panet_fused<<<512, 512, LDS_BYTES, stream>>>(x, y, w1, b1, w2, b2, w3, b3, wd, bd,
                                               (float*)d_out);
}

// Round 4
// 82.195 us; speedup vs baseline: 2.8851x; 1.1075x over previous
//
#include <hip/hip_runtime.h>

// ---------------------------------------------------------------------------
// PANet disparity head, fused single kernel for MI355X (gfx950).
//
// Math:  xf,yf = encoder(x), encoder(y)   (B,H,W scalar maps)
//        logits_x[o,w] = yf[w] * sum_d wd[o,d]*xf[w+d] + bd[o]
//        logits_y[o,w] = xf[w] * sum_d wd[o,d]*yf[w-d] + bd[o]
//        disp = sum_o o*softmax_o(logits)
// One block per (b,h) row; encoder + both correlation GEMMs + softmax fused.
//
// R1/R2: 128-VGPR cap spilled 96-reg accumulator -> 258 MB scratch. Fixed in
// R3 via online softmax (live set 88 VGPR) + waves_per_eu. R3 showed
// MfmaUtil 16% / VALUBusy 44% / occupancy 20% (2 waves/SIMD, 101KB LDS = 1
// block/CU): MFMA idles while each wave runs its softmax VALU burst.
// R4: 1024-thread blocks -> 16 waves on the same 1 block/CU = 4 waves/SIMD.
// 88 VGPR fits the 128 cap of 4 waves/EU exactly. Geometry halves per-wave.
// ---------------------------------------------------------------------------

typedef __attribute__((ext_vector_type(8))) __bf16 bf16x8;
typedef __attribute__((ext_vector_type(4))) float  f32x4;

#define MFMA16x16x32(a,b,c) __builtin_amdgcn_mfma_f32_16x16x32_bf16((a),(b),(c),0,0,0)

constexpr int CH = 32, HH = 256, WW = 512, DD = 192;
constexpr int HW  = HH * WW;        // 131072
constexpr int CHW = CH * HW;        // 4194304
constexpr int OUTPLANE = 2 * HH * WW; // 262144 (B*H*W)

// LDS layout (bytes). wd rows are 384 B (192 bf16), XOR-swizzled by (o&7)<<4.
constexpr int WD_OFF  = 0;
constexpr int WD_SZ   = 192 * 384;            // 73728
constexpr int CPS     = 1424;                 // hankel copy stride (712 bf16)
constexpr int XC_OFF  = WD_OFF + WD_SZ;       // 73728: 8 shifted copies of xf
constexpr int YC_OFF  = XC_OFF + 8 * CPS;     // 85120: 8 shifted copies of rev(yf)
constexpr int SCY_OFF = YC_OFF + 8 * CPS;     // 96512: yf f32[512]
constexpr int SCX_OFF = SCY_OFF + 2048;       // 98560: xf f32[512]
constexpr int BD_OFF  = SCX_OFF + 2048;       // 100608: bd f32[192]
constexpr int LDS_BYTES = BD_OFF + 768;       // 101376

__global__ __launch_bounds__(1024)
__attribute__((amdgpu_waves_per_eu(4, 4)))
void panet_fused(const float* __restrict__ gx,  const float* __restrict__ gy,
                 const float* __restrict__ gw1, const float* __restrict__ gb1,
                 const float* __restrict__ gw2, const float* __restrict__ gb2,
                 const float* __restrict__ gw3, const float* __restrict__ gb3,
                 const float* __restrict__ gwd, const float* __restrict__ gbd,
                 float* __restrict__ gout)
{
  extern __shared__ __align__(16) char lds[];
  const int tid  = threadIdx.x;
  const int bh   = blockIdx.x;
  const int b    = bh >> 8;
  const int h    = bh & 255;
  const int lane = tid & 63;
  const int m    = lane & 15;   // MFMA row/col within 16
  const int g    = lane >> 4;   // MFMA lane group
  const int wid  = tid >> 6;    // wave id, 16 waves

  // ------------------------------------------------------------- phase 0
  {
    int* zp = (int*)(lds + XC_OFF);
    #pragma unroll 4
    for (int i = tid; i < (16 * CPS) / 4; i += 1024) zp[i] = 0;

    unsigned short* wds = (unsigned short*)(lds + WD_OFF);
    for (int i = tid; i < 192 * 192; i += 1024) {
      const int o = i / 192;
      const int k = i - o * 192;
      const __bf16 v = (__bf16)gwd[i];
      const int byt = o * 384 + ((2 * k) ^ ((o & 7) << 4));
      wds[byt >> 1] = __builtin_bit_cast(unsigned short, v);
    }
    float* bds = (float*)(lds + BD_OFF);
    if (tid < 192) bds[tid] = gbd[tid];
  }
  __syncthreads();

  // ------------------------------------------------------------- phase 1
  // Encoder via MFMA. Slot map for layers 1/2: psi(g,j) = 16*(j>>2)+4g+(j&3).
  {
    bf16x8 A1[4], A2[2][2];
    f32x4  bias1[4], bias2[2], w3v[2];
    #pragma unroll
    for (int Mt = 0; Mt < 4; ++Mt) {
      const float* p = gw1 + (16 * Mt + m) * 32 + 4 * g;
      const f32x4 u0 = *(const f32x4*)p;
      const f32x4 u1 = *(const f32x4*)(p + 16);
      #pragma unroll
      for (int j = 0; j < 4; ++j) { A1[Mt][j] = (__bf16)u0[j]; A1[Mt][j + 4] = (__bf16)u1[j]; }
      bias1[Mt] = *(const f32x4*)(gb1 + 16 * Mt + 4 * g);
    }
    #pragma unroll
    for (int Mt = 0; Mt < 2; ++Mt) {
      #pragma unroll
      for (int s = 0; s < 2; ++s) {
        const float* p = gw2 + (16 * Mt + m) * 64 + 32 * s + 4 * g;
        const f32x4 u0 = *(const f32x4*)p;
        const f32x4 u1 = *(const f32x4*)(p + 16);
        #pragma unroll
        for (int j = 0; j < 4; ++j) { A2[Mt][s][j] = (__bf16)u0[j]; A2[Mt][s][j + 4] = (__bf16)u1[j]; }
      }
      bias2[Mt] = *(const f32x4*)(gb2 + 16 * Mt + 4 * g);
      w3v[Mt]   = *(const f32x4*)(gw3 + 16 * Mt + 4 * g);
    }
    const float b3s = gb3[0];
    const f32x4 zf4 = {0.f, 0.f, 0.f, 0.f};

    for (int u = wid; u < 64; u += 16) {         // 2 images x 32 col-tiles
      const int t  = u >> 5;
      const int w0 = (u & 31) << 4;
      const float* src = (t ? gy : gx) + b * CHW + h * WW + w0 + m;

      bf16x8 B1;
      #pragma unroll
      for (int j = 0; j < 8; ++j) {
        const int c = 16 * (j >> 2) + 4 * g + (j & 3);
        B1[j] = (__bf16)fmaxf(src[c * HW], 0.f);
      }
      f32x4 acc1[4];
      #pragma unroll
      for (int Mt = 0; Mt < 4; ++Mt) acc1[Mt] = MFMA16x16x32(A1[Mt], B1, zf4);

      bf16x8 B2[2];
      #pragma unroll
      for (int s = 0; s < 2; ++s) {
        #pragma unroll
        for (int j = 0; j < 4; ++j) {
          B2[s][j]     = (__bf16)fmaxf(acc1[2 * s][j]     + bias1[2 * s][j],     0.f);
          B2[s][j + 4] = (__bf16)fmaxf(acc1[2 * s + 1][j] + bias1[2 * s + 1][j], 0.f);
        }
      }
      f32x4 acc2[2];
      #pragma unroll
      for (int Mt = 0; Mt < 2; ++Mt)
        acc2[Mt] = MFMA16x16x32(A2[Mt][1], B2[1], MFMA16x16x32(A2[Mt][0], B2[0], zf4));

      float s3 = 0.f;
      #pragma unroll
      for (int Mt = 0; Mt < 2; ++Mt)
        #pragma unroll
        for (int r = 0; r < 4; ++r)
          s3 += w3v[Mt][r] * fmaxf(acc2[Mt][r] + bias2[Mt][r], 0.f);
      s3 += __shfl_xor(s3, 16);
      s3 += __shfl_xor(s3, 32);
      const float val = fmaxf(s3 + b3s, 0.f);

      if (lane < 16) {
        const int px = w0 + m;
        const unsigned short bits = __builtin_bit_cast(unsigned short, (__bf16)val);
        if (t == 0) {
          ((float*)(lds + SCX_OFF))[px] = val;
          #pragma unroll
          for (int c = 0; c < 8; ++c) {           // copy_c[e] = xf[e+c]
            const int e = px - c;
            if (e >= 0) ((unsigned short*)(lds + XC_OFF + c * CPS))[e] = bits;
          }
        } else {
          ((float*)(lds + SCY_OFF))[px] = val;
          #pragma unroll
          for (int c = 0; c < 8; ++c) {           // rev copy: ry[e] = yf[511-e]
            const int e = 511 - px - c;
            if (e >= 0) ((unsigned short*)(lds + YC_OFF + c * CPS))[e] = bits;
          }
        }
      }
    }
  }
  __syncthreads();

  // ------------------------------------------------------------- phase 2
  // Correlation GEMM + ONLINE softmax. B-fragments hoisted (48 VGPRs), then
  // 192 output rows processed in 6 Mt-pairs; per pair only 16 acc regs live.
  // Waves 0-7: x-direction, waves 8-15: y-direction; 64 cols per wave.
  {
    const int dir      = wid >> 3;
    const int colbase  = (wid & 7) << 6;
    const char* Bb     = lds + (dir ? YC_OFF : XC_OFF);
    const float* scrow = (const float*)(lds + (dir ? SCX_OFF : SCY_OFF));
    float* outp = gout + dir * OUTPLANE + (((b << 8) + h) << 9);
    const int Xm   = (m & 7) << 4;
    const int arow = m * 384;
    const float g4 = 4.0f * (float)g;

    for (int chunk = 0; chunk < 2; ++chunk) {
      const int n0 = colbase + (chunk << 5);
      int   laneB[2];
      float sc[2];
      #pragma unroll
      for (int nt = 0; nt < 2; ++nt) {
        const int wc = n0 + 16 * nt + m;
        const int I0 = dir ? (511 - wc) : wc;     // hankel base element
        const int c  = I0 & 7;                    // which shifted copy
        laneB[nt] = c * CPS + 2 * (I0 - c) + 16 * g;
        sc[nt] = scrow[wc];
      }
      bf16x8 bfr[6][2];
      #pragma unroll
      for (int ks = 0; ks < 6; ++ks) {            // K = 6*32 = 192
        bfr[ks][0] = *(const bf16x8*)(Bb + laneB[0] + (ks << 6));
        bfr[ks][1] = *(const bf16x8*)(Bb + laneB[1] + (ks << 6));
      }

      float mx0 = -3.4e38f, mx1 = -3.4e38f;
      float s0 = 0.f, s1 = 0.f, ws0 = 0.f, ws1 = 0.f;

      #pragma unroll 2
      for (int mp = 0; mp < 6; ++mp) {            // Mt pair = rows 32mp..32mp+31
        f32x4 a00 = {0,0,0,0}, a01 = {0,0,0,0}, a10 = {0,0,0,0}, a11 = {0,0,0,0};
        #pragma unroll
        for (int ks = 0; ks < 6; ++ks) {
          const int inner = ((ks << 6) + (g << 4)) ^ Xm;
          const char* ap = lds + WD_OFF + (mp * 2) * 6144 + arow + inner;
          const bf16x8 af0 = *(const bf16x8*)(ap);
          const bf16x8 af1 = *(const bf16x8*)(ap + 6144);
          a00 = MFMA16x16x32(af0, bfr[ks][0], a00);
          a01 = MFMA16x16x32(af0, bfr[ks][1], a01);
          a10 = MFMA16x16x32(af1, bfr[ks][0], a10);
          a11 = MFMA16x16x32(af1, bfr[ks][1], a11);
        }
        const f32x4 bd0 = *(const f32x4*)(lds + BD_OFF + (mp * 2) * 64 + 16 * g);
        const f32x4 bd1 = *(const f32x4*)(lds + BD_OFF + (mp * 2 + 1) * 64 + 16 * g);
        const float ob = (float)(32 * mp);        // o = 32mp + 16tt + 4g + r (4g added at end)

        {                                          // nt = 0
          f32x4 L0, L1;
          #pragma unroll
          for (int r = 0; r < 4; ++r) {
            L0[r] = fmaf(sc[0], a00[r], bd0[r]);
            L1[r] = fmaf(sc[0], a10[r], bd1[r]);
          }
          const float pm = fmaxf(fmaxf(fmaxf(L0[0], L0[1]), fmaxf(L0[2], L0[3])),
                                 fmaxf(fmaxf(L1[0], L1[1]), fmaxf(L1[2], L1[3])));
          const float nm = fmaxf(mx0, pm);
          const float f  = __expf(mx0 - nm);
          float ls = 0.f, lw = 0.f;
          #pragma unroll
          for (int r = 0; r < 4; ++r) {
            const float p0 = __expf(L0[r] - nm);
            const float p1 = __expf(L1[r] - nm);
            ls += p0 + p1;
            lw += (ob + (float)r) * p0 + (ob + 16.f + (float)r) * p1;
          }
          s0  = fmaf(s0,  f, ls);
          ws0 = fmaf(ws0, f, lw);
          mx0 = nm;
        }
        {                                          // nt = 1
          f32x4 L0, L1;
          #pragma unroll
          for (int r = 0; r < 4; ++r) {
            L0[r] = fmaf(sc[1], a01[r], bd0[r]);
            L1[r] = fmaf(sc[1], a11[r], bd1[r]);
          }
          const float pm = fmaxf(fmaxf(fmaxf(L0[0], L0[1]), fmaxf(L0[2], L0[3])),
                                 fmaxf(fmaxf(L1[0], L1[1]), fmaxf(L1[2], L1[3])));
          const float nm = fmaxf(mx1, pm);
          const float f  = __expf(mx1 - nm);
          float ls = 0.f, lw = 0.f;
          #pragma unroll
          for (int r = 0; r < 4; ++r) {
            const float p0 = __expf(L0[r] - nm);
            const float p1 = __expf(L1[r] - nm);
            ls += p0 + p1;
            lw += (ob + (float)r) * p0 + (ob + 16.f + (float)r) * p1;
          }
          s1  = fmaf(s1,  f, ls);
          ws1 = fmaf(ws1, f, lw);
          mx1 = nm;
        }
      }

      // cross-lane combine: rescale each lane's partial to the group max first
      #pragma unroll
      for (int nt = 0; nt < 2; ++nt) {
        const float mx = nt ? mx1 : mx0;
        const float s  = nt ? s1  : s0;
        const float ws = nt ? ws1 : ws0;
        float M = fmaxf(mx, __shfl_xor(mx, 16));
        M = fmaxf(M, __shfl_xor(M, 32));
        const float f = __expf(mx - M);
        float sr = s * f;
        float wr = (ws + g4 * s) * f;
        sr += __shfl_xor(sr, 16); sr += __shfl_xor(sr, 32);
        wr += __shfl_xor(wr, 16); wr += __shfl_xor(wr, 32);
        if (lane < 16) outp[n0 + 16 * nt + m] = wr / sr;
      }
    }
  }
}

extern "C" void kernel_launch(void* const* d_in, const int* in_sizes, int n_in,
                              void* d_out, int out_size, void* d_ws, size_t ws_size,
                              hipStream_t stream) {
  const float* x  = (const float*)d_in[0];
  const float* y  = (const float*)d_in[1];
  const float* w1 = (const float*)d_in[2];
  const float* b1 = (const float*)d_in[3];
  const float* w2 = (const float*)d_in[4];
  const float* b2 = (const float*)d_in[5];
  const float* w3 = (const float*)d_in[6];
  const float* b3 = (const float*)d_in[7];
  const float* wd = (const float*)d_in[8];
  const float* bd = (const float*)d_in[9];

  // >64KB dynamic LDS: set the opt-in attribute (harmless if not required).
  (void)hipFuncSetAttribute((const void*)panet_fused,
                            hipFuncAttributeMaxDynamicSharedMemorySize, LDS_BYTES);
  panet_fused<<<512, 1024, LDS_BYTES, stream>>>(x, y, w1, b1, w2, b2, w3, b3, wd, bd,
                                                (float*)d_out);
}